// Round 10
// baseline (231.184 us; speedup 1.0000x reference)
//
#include <hip/hip_runtime.h>

// CombinedActorModel R14: all-tiles-up-front spatial prefetch.
// R13 post-mortem: pairing (2x ILP, half the frag ds_reads) was NULL -- and it
// silently removed R11's cross-tile load prefetch, exposing the ~300cy
// scattered spatial-load latency twice per wave (16 loads -> immediate
// cndmask/pack -> s_waitcnt right on the critical path).
// R14: issue ALL 32 spatial loads (4 tiles x 8 dwords/lane) at the top of the
// kernel, before frag staging; pack f32->f16 right before __syncthreads
// (vmcnt wait merges with the staging wait, ~free); compute both pairs with
// ZERO VMEM inside. Raw-f32 staging is +32 VGPR transient, freed at pack.
// Everything else (paired compute sharing frag reads, bias folding into
// spare K-slots, LDS frag image + pinned-index ds_read_b128, 512-thread
// blocks, TPB=4, LDS-compacted coalesced stores) unchanged from R13.

typedef _Float16 half8   __attribute__((ext_vector_type(8)));
typedef __fp16   fp16x2  __attribute__((ext_vector_type(2)));
typedef float    floatx4 __attribute__((ext_vector_type(4)));

#define NFRAG 21                    // 3 actors * (4 stage1 + 2 stage2 + 1 stage3)
#define FRAG_HALFS (NFRAG * 512)    // 10752 halfs = 21504 B
#define TPB 4                       // tiles per block (tile = 128 elements)
#define NWAVES 8                    // 512-thread blocks

__global__ __launch_bounds__(256) void prep_frags(
    const float* __restrict__ Wmx, const float* __restrict__ bmx,
    const float* __restrict__ Wnx, const float* __restrict__ bnx,
    const float* __restrict__ Wmy, const float* __restrict__ bmy,
    const float* __restrict__ Wny, const float* __restrict__ bny,
    const float* __restrict__ Wmz, const float* __restrict__ bmz,
    const float* __restrict__ Wnz, const float* __restrict__ bnz,
    const float* __restrict__ Wlin, const float* __restrict__ blin,
    const float* __restrict__ Wout, const float* __restrict__ bout,
    _Float16* __restrict__ frag)
{
    int i = threadIdx.x + blockIdx.x * blockDim.x;
    if (i >= FRAG_HALFS) return;
    int f = i >> 9, rem = i & 511;
    int lane = rem >> 3, j = rem & 7;
    int q = lane >> 4, m = lane & 15;
    int a = f / 7, idx = f % 7;
    float v = 0.f;
    if (idx < 4) {
        int c = m + ((idx & 1) ? 16 : 0);
        int k = 8 * q + j;
        bool npart = (idx >= 2);
        if (c < 10) {
            if (!npart) { if (k < 6)             v = Wmx[(a*10 + c)*6 + k];
                          else if (k == 27)      v = bmx[a*10 + c]; }
            else        { if (k >= 6 && k < 9)   v = Wnx[(a*10 + c)*3 + (k-6)];
                          else if (k == 27)      v = bnx[a*10 + c]; }
        } else if (c < 20) {
            if (!npart) { if (k >= 9 && k < 15)  v = Wmy[(a*10 + c-10)*6 + (k-9)];
                          else if (k == 27)      v = bmy[a*10 + c-10]; }
            else        { if (k >= 15 && k < 18) v = Wny[(a*10 + c-10)*3 + (k-15)];
                          else if (k == 27)      v = bny[a*10 + c-10]; }
        } else if (c < 25) {
            if (!npart) { if (k >= 18 && k < 24) v = Wmz[(a*5 + c-20)*6 + (k-18)];
                          else if (k == 27)      v = bmz[a*5 + c-20]; }
            else        { if (k >= 24 && k < 27) v = Wnz[(a*5 + c-20)*3 + (k-24)];
                          else if (k == 27)      v = bnz[a*5 + c-20]; }
        }
    } else if (idx < 6) {
        int o  = m + ((idx == 5) ? 16 : 0);
        int kc = 16 * (j >> 2) + 4 * q + (j & 3);   // sigma(q,j)
        if (o < 25) {
            if (kc < 25)       v = Wlin[(a*25 + o)*25 + kc];
            else if (kc == 25) v = blin[a*25 + o];
        }
    } else {
        int ko = 16 * (j >> 2) + 4 * q + (j & 3);
        if (m < 10) {
            if (ko < 25)       v = Wout[(a*15 + m)*25 + ko];
            else if (ko == 25) v = bout[a*15 + m];
        }
    }
    frag[(size_t)f * 512 + lane * 8 + j] = (_Float16)v;
}

__global__ __launch_bounds__(512) void actor_mfma(
    const float* __restrict__ spatial,
    const _Float16* __restrict__ frag,
    float* __restrict__ out)
{
    __shared__ _Float16 lds_f[FRAG_HALFS];     // 21504 B, block-shared constants
    __shared__ float    lds_o[NWAVES * 144];   // per-wave output compaction

    const int t = threadIdx.x;
    const int lane = t & 63, w = t >> 6;
    const int q = lane >> 4, e = lane & 15;
    const size_t b0 = (size_t)blockIdx.x * (16 * NWAVES * TPB);

    const float* sbase = spatial + (b0 + (size_t)(w * 16 + e)) * 27 + 8 * q;

    // ---- 1. issue ALL spatial loads up front (4 tiles x 8 dwords, raw f32).
    // k>=27 slots pre-zeroed; loads are exec-masked. Latency buried under the
    // frag staging + barrier below.
    float sA[8], sB[8], sC[8], sD[8];
    {
        const float* s0 = sbase;
        const float* s1 = sbase + (size_t)(16 * NWAVES * 27);
        const float* s2 = sbase + (size_t)2 * (16 * NWAVES * 27);
        const float* s3 = sbase + (size_t)3 * (16 * NWAVES * 27);
        #pragma unroll
        for (int j = 0; j < 8; ++j) {
            int k = 8 * q + j;
            sA[j] = 0.f; sB[j] = 0.f; sC[j] = 0.f; sD[j] = 0.f;
            if (k < 27) {
                sA[j] = s0[j]; sB[j] = s1[j]; sC[j] = s2[j]; sD[j] = s3[j];
            }
        }
    }

    // ---- 2. cooperative frag staging: 1344 float4, once per block
    {
        const float4* gf = (const float4*)frag;
        float4* df = (float4*)lds_f;
        #pragma unroll
        for (int k = 0; k < 3; ++k) {
            int idx = t + k * 512;
            if (idx < 1344) df[idx] = gf[idx];
        }
    }

    union H8u { half8 v; fp16x2 p[4]; };

    // ---- 3. pack f32->f16 (waits on the spatial loads here, overlapping the
    // staging drain); bias slot k==27 -> 1.0
    H8u BsA, BsB, BsC, BsD;
    {
        auto packBs = [&](H8u& d, const float (&s)[8]) {
            float tmp[8];
            #pragma unroll
            for (int j = 0; j < 8; ++j) {
                int k = 8 * q + j;
                tmp[j] = (k == 27) ? 1.f : s[j];
            }
            #pragma unroll
            for (int p_ = 0; p_ < 4; ++p_)
                d.p[p_] = __builtin_amdgcn_cvt_pkrtz(tmp[2*p_], tmp[2*p_+1]);
        };
        packBs(BsA, sA); packBs(BsB, sB); packBs(BsC, sC); packBs(BsD, sD);
    }

    float* const ldso = lds_o + w * 144;
    const floatx4 z = {0.f, 0.f, 0.f, 0.f};

    __syncthreads();

    // 32-bit LDS half8-index; opaquely re-pinned per actor so the 21
    // loop-invariant ds_reads can't be hoisted into (and spill) registers.
    int fo = lane;

    auto ss = [](float v_) {
        return v_ * __builtin_amdgcn_rcpf(1.0f + __builtin_fabsf(v_));
    };

    auto epilogue = [&](const floatx4 (&oacc)[3], int tt) {
        // softmax over actors of ch9, weighted sum of ch0..8
        const int src9 = 32 + e;   // lane (e, q=2); its reg1 = ch9
        float g0 = __shfl(oacc[0][1], src9, 64);
        float g1 = __shfl(oacc[1][1], src9, 64);
        float g2 = __shfl(oacc[2][1], src9, 64);
        float mx = fmaxf(g0, fmaxf(g1, g2));
        float e0 = __expf(g0 - mx);
        float e1 = __expf(g1 - mx);
        float e2 = __expf(g2 - mx);
        float inv = __builtin_amdgcn_rcpf(e0 + e1 + e2);
        e0 *= inv; e1 *= inv; e2 *= inv;

        float res[4];
        #pragma unroll
        for (int r = 0; r < 4; ++r)
            res[r] = oacc[0][r] * e0 + oacc[1][r] * e1 + oacc[2][r] * e2;

        // compact to this wave's scratch, coalesced float4 store
        if (q < 2) {
            #pragma unroll
            for (int r = 0; r < 4; ++r) ldso[e * 9 + 4 * q + r] = res[r];
        } else if (q == 2) {
            ldso[e * 9 + 8] = res[0];
        }
        // same-wave DS ordering: writes retire before the reads below issue
        if (lane < 36) {
            float4 v = *(const float4*)(ldso + lane * 4);
            *(float4*)(out + (b0 + (size_t)tt * (16 * NWAVES) + w * 16) * 9 + lane * 4) = v;
        }
    };

    // ---- paired-tile compute: one frag read set feeds two tile chains
    auto pairCompute = [&](const H8u& BsX, const H8u& BsY, int ta, int tb) {
        floatx4 oaccA[3], oaccB[3];
        #pragma unroll
        for (int a = 0; a < 3; ++a) {
            asm volatile("" : "+v"(fo));   // opaque: blocks LICM/clustering
            const half8* fp = (const half8*)lds_f + fo;
            const int fb = a * 7;

            // stage1 low half (frags 0,2 shared by both tiles)
            H8u PA, PB;
            {
                half8 f0 = fp[(fb+0)*64], f2 = fp[(fb+2)*64];
                floatx4 MA0 = __builtin_amdgcn_mfma_f32_16x16x32_f16(f0, BsX.v, z, 0,0,0);
                floatx4 NA0 = __builtin_amdgcn_mfma_f32_16x16x32_f16(f2, BsX.v, z, 0,0,0);
                floatx4 MB0 = __builtin_amdgcn_mfma_f32_16x16x32_f16(f0, BsY.v, z, 0,0,0);
                floatx4 NB0 = __builtin_amdgcn_mfma_f32_16x16x32_f16(f2, BsY.v, z, 0,0,0);
                PA.p[0] = __builtin_amdgcn_cvt_pkrtz(MA0[0]*NA0[0], MA0[1]*NA0[1]);
                PA.p[1] = __builtin_amdgcn_cvt_pkrtz(MA0[2]*NA0[2], MA0[3]*NA0[3]);
                PB.p[0] = __builtin_amdgcn_cvt_pkrtz(MB0[0]*NB0[0], MB0[1]*NB0[1]);
                PB.p[1] = __builtin_amdgcn_cvt_pkrtz(MB0[2]*NB0[2], MB0[3]*NB0[3]);
            }
            // stage1 high half (frags 1,3); sigma slot kc=25 (q=2, elem 5)
            // carries the stage2 bias column -> force 1.0
            {
                half8 f1 = fp[(fb+1)*64], f3 = fp[(fb+3)*64];
                floatx4 MA1 = __builtin_amdgcn_mfma_f32_16x16x32_f16(f1, BsX.v, z, 0,0,0);
                floatx4 NA1 = __builtin_amdgcn_mfma_f32_16x16x32_f16(f3, BsX.v, z, 0,0,0);
                floatx4 MB1 = __builtin_amdgcn_mfma_f32_16x16x32_f16(f1, BsY.v, z, 0,0,0);
                floatx4 NB1 = __builtin_amdgcn_mfma_f32_16x16x32_f16(f3, BsY.v, z, 0,0,0);
                float gA5 = (q == 2) ? 1.f : MA1[1]*NA1[1];
                float gB5 = (q == 2) ? 1.f : MB1[1]*NB1[1];
                PA.p[2] = __builtin_amdgcn_cvt_pkrtz(MA1[0]*NA1[0], gA5);
                PA.p[3] = __builtin_amdgcn_cvt_pkrtz(MA1[2]*NA1[2], MA1[3]*NA1[3]);
                PB.p[2] = __builtin_amdgcn_cvt_pkrtz(MB1[0]*NB1[0], gB5);
                PB.p[3] = __builtin_amdgcn_cvt_pkrtz(MB1[2]*NB1[2], MB1[3]*NB1[3]);
            }

            // stage2 (frags 4,5 shared)
            H8u HhA, HhB;
            {
                half8 f4 = fp[(fb+4)*64], f5 = fp[(fb+5)*64];
                floatx4 HA0 = __builtin_amdgcn_mfma_f32_16x16x32_f16(f4, PA.v, z, 0,0,0);
                floatx4 HA1 = __builtin_amdgcn_mfma_f32_16x16x32_f16(f5, PA.v, z, 0,0,0);
                floatx4 HB0 = __builtin_amdgcn_mfma_f32_16x16x32_f16(f4, PB.v, z, 0,0,0);
                floatx4 HB1 = __builtin_amdgcn_mfma_f32_16x16x32_f16(f5, PB.v, z, 0,0,0);
                HhA.p[0] = __builtin_amdgcn_cvt_pkrtz(ss(HA0[0]), ss(HA0[1]));
                HhA.p[1] = __builtin_amdgcn_cvt_pkrtz(ss(HA0[2]), ss(HA0[3]));
                float hA5 = (q == 2) ? 1.f : ss(HA1[1]);
                HhA.p[2] = __builtin_amdgcn_cvt_pkrtz(ss(HA1[0]), hA5);
                HhA.p[3] = __builtin_amdgcn_cvt_pkrtz(ss(HA1[2]), ss(HA1[3]));
                HhB.p[0] = __builtin_amdgcn_cvt_pkrtz(ss(HB0[0]), ss(HB0[1]));
                HhB.p[1] = __builtin_amdgcn_cvt_pkrtz(ss(HB0[2]), ss(HB0[3]));
                float hB5 = (q == 2) ? 1.f : ss(HB1[1]);
                HhB.p[2] = __builtin_amdgcn_cvt_pkrtz(ss(HB1[0]), hB5);
                HhB.p[3] = __builtin_amdgcn_cvt_pkrtz(ss(HB1[2]), ss(HB1[3]));
            }

            // stage3 (frag 6 shared); lane (e,q) reg r holds ch = 4q+r
            {
                half8 f6 = fp[(fb+6)*64];
                oaccA[a] = __builtin_amdgcn_mfma_f32_16x16x32_f16(f6, HhA.v, z, 0,0,0);
                oaccB[a] = __builtin_amdgcn_mfma_f32_16x16x32_f16(f6, HhB.v, z, 0,0,0);
            }
        }

        epilogue(oaccA, ta);
        epilogue(oaccB, tb);
    };

    pairCompute(BsA, BsB, 0, 1);
    pairCompute(BsC, BsD, 2, 3);
}

extern "C" void kernel_launch(void* const* d_in, const int* in_sizes, int n_in,
                              void* d_out, int out_size, void* d_ws, size_t ws_size,
                              hipStream_t stream) {
    const float* spatial = (const float*)d_in[0];
    // d_in[1] = car_stats: unused by the model, never read.
    const float* Wmx  = (const float*)d_in[2];
    const float* bmx  = (const float*)d_in[3];
    const float* Wnx  = (const float*)d_in[4];
    const float* bnx  = (const float*)d_in[5];
    const float* Wmy  = (const float*)d_in[6];
    const float* bmy  = (const float*)d_in[7];
    const float* Wny  = (const float*)d_in[8];
    const float* bny  = (const float*)d_in[9];
    const float* Wmz  = (const float*)d_in[10];
    const float* bmz  = (const float*)d_in[11];
    const float* Wnz  = (const float*)d_in[12];
    const float* bnz  = (const float*)d_in[13];
    const float* Wlin = (const float*)d_in[14];
    const float* blin = (const float*)d_in[15];
    const float* Wout = (const float*)d_in[16];
    const float* bout = (const float*)d_in[17];
    float* out = (float*)d_out;

    _Float16* frag = (_Float16*)d_ws;   // 21504 B

    prep_frags<<<dim3(42), dim3(256), 0, stream>>>(
        Wmx, bmx, Wnx, bnx, Wmy, bmy, Wny, bny, Wmz, bmz, Wnz, bnz,
        Wlin, blin, Wout, bout, frag);

    const int nb = in_sizes[0] / 27;           // 1048576, multiple of 16*NWAVES*TPB
    dim3 grid(nb / (16 * NWAVES * TPB));       // 2048 blocks, 8 waves each
    actor_mfma<<<grid, dim3(64 * NWAVES), 0, stream>>>(spatial, frag, out);
}

// Round 11
// 227.336 us; speedup vs baseline: 1.0169x; 1.0169x over previous
//
#include <hip/hip_runtime.h>

// CombinedActorModel R15: R12b exactly, with TPB 4->8 (grid 1024).
// R13 (pairing/ILP) was null; R14 (hoist-all-loads) regressed ~7us -- the
// R12b per-tile ping-pong schedule is locally optimal. Remaining lever is
// residency geometry: TPB=4 ran 2048 blocks = 8/CU in two sequential
// generations (LDS 26.1KB -> max 6 resident). TPB=8 -> 1024 blocks = exactly
// 4/CU: ALL blocks co-resident from t=0 (4 <= 6 LDS cap; VGPR ~40 <= 64 keeps
// 8 waves/SIMD -> 32 waves/CU = 100% cap), no block turnover, no tail, and
// frag staging traffic halved. Everything else byte-identical to R12b
// (cvt_pkrtz packs, bias folded into spare K-slots, LDS frag image +
// pinned-index ds_read_b128, ping-pong spatial prefetch, 512-thread blocks,
// LDS-compacted coalesced stores).

typedef _Float16 half8   __attribute__((ext_vector_type(8)));
typedef __fp16   fp16x2  __attribute__((ext_vector_type(2)));
typedef float    floatx4 __attribute__((ext_vector_type(4)));

#define NFRAG 21                    // 3 actors * (4 stage1 + 2 stage2 + 1 stage3)
#define FRAG_HALFS (NFRAG * 512)    // 10752 halfs = 21504 B
#define TPB 8                       // tiles per block (tile = 128 elements)
#define NWAVES 8                    // 512-thread blocks

__global__ __launch_bounds__(256) void prep_frags(
    const float* __restrict__ Wmx, const float* __restrict__ bmx,
    const float* __restrict__ Wnx, const float* __restrict__ bnx,
    const float* __restrict__ Wmy, const float* __restrict__ bmy,
    const float* __restrict__ Wny, const float* __restrict__ bny,
    const float* __restrict__ Wmz, const float* __restrict__ bmz,
    const float* __restrict__ Wnz, const float* __restrict__ bnz,
    const float* __restrict__ Wlin, const float* __restrict__ blin,
    const float* __restrict__ Wout, const float* __restrict__ bout,
    _Float16* __restrict__ frag)
{
    int i = threadIdx.x + blockIdx.x * blockDim.x;
    if (i >= FRAG_HALFS) return;
    int f = i >> 9, rem = i & 511;
    int lane = rem >> 3, j = rem & 7;
    int q = lane >> 4, m = lane & 15;
    int a = f / 7, idx = f % 7;
    float v = 0.f;
    if (idx < 4) {
        int c = m + ((idx & 1) ? 16 : 0);
        int k = 8 * q + j;
        bool npart = (idx >= 2);
        if (c < 10) {
            if (!npart) { if (k < 6)             v = Wmx[(a*10 + c)*6 + k];
                          else if (k == 27)      v = bmx[a*10 + c]; }
            else        { if (k >= 6 && k < 9)   v = Wnx[(a*10 + c)*3 + (k-6)];
                          else if (k == 27)      v = bnx[a*10 + c]; }
        } else if (c < 20) {
            if (!npart) { if (k >= 9 && k < 15)  v = Wmy[(a*10 + c-10)*6 + (k-9)];
                          else if (k == 27)      v = bmy[a*10 + c-10]; }
            else        { if (k >= 15 && k < 18) v = Wny[(a*10 + c-10)*3 + (k-15)];
                          else if (k == 27)      v = bny[a*10 + c-10]; }
        } else if (c < 25) {
            if (!npart) { if (k >= 18 && k < 24) v = Wmz[(a*5 + c-20)*6 + (k-18)];
                          else if (k == 27)      v = bmz[a*5 + c-20]; }
            else        { if (k >= 24 && k < 27) v = Wnz[(a*5 + c-20)*3 + (k-24)];
                          else if (k == 27)      v = bnz[a*5 + c-20]; }
        }
    } else if (idx < 6) {
        int o  = m + ((idx == 5) ? 16 : 0);
        int kc = 16 * (j >> 2) + 4 * q + (j & 3);   // sigma(q,j)
        if (o < 25) {
            if (kc < 25)       v = Wlin[(a*25 + o)*25 + kc];
            else if (kc == 25) v = blin[a*25 + o];
        }
    } else {
        int ko = 16 * (j >> 2) + 4 * q + (j & 3);
        if (m < 10) {
            if (ko < 25)       v = Wout[(a*15 + m)*25 + ko];
            else if (ko == 25) v = bout[a*15 + m];
        }
    }
    frag[(size_t)f * 512 + lane * 8 + j] = (_Float16)v;
}

__global__ __launch_bounds__(512) void actor_mfma(
    const float* __restrict__ spatial,
    const _Float16* __restrict__ frag,
    float* __restrict__ out)
{
    __shared__ _Float16 lds_f[FRAG_HALFS];     // 21504 B, block-shared constants
    __shared__ float    lds_o[NWAVES * 144];   // per-wave output compaction

    const int t = threadIdx.x;
    const int lane = t & 63, w = t >> 6;
    const int q = lane >> 4, e = lane & 15;
    const size_t b0 = (size_t)blockIdx.x * (16 * NWAVES * TPB);

    // ---- cooperative frag staging: 1344 float4, once per block
    {
        const float4* gf = (const float4*)frag;
        float4* df = (float4*)lds_f;
        #pragma unroll
        for (int k = 0; k < 3; ++k) {
            int idx = t + k * 512;
            if (idx < 1344) df[idx] = gf[idx];
        }
    }

    // ---- per-lane constants for the spatial gather (invariant across tiles)
    const float* sbase = spatial + (b0 + (size_t)(w * 16 + e)) * 27 + 8 * q;
    float vbase[8];
    #pragma unroll
    for (int j = 0; j < 8; ++j) vbase[j] = ((8 * q + j) == 27) ? 1.f : 0.f;

    float* const ldso = lds_o + w * 144;
    const floatx4 z = {0.f, 0.f, 0.f, 0.f};

    __syncthreads();

    // 32-bit LDS half8-index; opaquely re-pinned per actor so the 21
    // loop-invariant ds_reads can't be hoisted into (and spill) registers.
    int fo = lane;

    auto loadT = [&](float (&dst)[8], int tt) {
        const float* s_ = sbase + (size_t)tt * (16 * NWAVES * 27);
        #pragma unroll
        for (int j = 0; j < 8; ++j) {
            int k = 8 * q + j;
            dst[j] = (k < 27) ? s_[j] : vbase[j];
        }
    };

    auto tileCompute = [&](const float (&cur)[8], int tt) {
        union H8u { half8 v; fp16x2 p[4]; };

        H8u Bs;
        #pragma unroll
        for (int p_ = 0; p_ < 4; ++p_)
            Bs.p[p_] = __builtin_amdgcn_cvt_pkrtz(cur[2*p_], cur[2*p_+1]);

        floatx4 oacc[3];
        #pragma unroll
        for (int a = 0; a < 3; ++a) {
            asm volatile("" : "+v"(fo));   // opaque: blocks LICM/clustering
            const half8* fp = (const half8*)lds_f + fo;
            const int fb = a * 7;
            // stage1: D[c][e]; ds_read_b128 at literal offsets feeds MFMA
            H8u P;
            {
                floatx4 M0 = __builtin_amdgcn_mfma_f32_16x16x32_f16(fp[(fb+0)*64], Bs.v, z, 0,0,0);
                floatx4 N0 = __builtin_amdgcn_mfma_f32_16x16x32_f16(fp[(fb+2)*64], Bs.v, z, 0,0,0);
                P.p[0] = __builtin_amdgcn_cvt_pkrtz(M0[0]*N0[0], M0[1]*N0[1]);
                P.p[1] = __builtin_amdgcn_cvt_pkrtz(M0[2]*N0[2], M0[3]*N0[3]);
            }
            {
                floatx4 M1 = __builtin_amdgcn_mfma_f32_16x16x32_f16(fp[(fb+1)*64], Bs.v, z, 0,0,0);
                floatx4 N1 = __builtin_amdgcn_mfma_f32_16x16x32_f16(fp[(fb+3)*64], Bs.v, z, 0,0,0);
                // sigma-packed slot kc=25 (q=2, elem 5) carries the stage2 bias
                float g5 = (q == 2) ? 1.f : M1[1]*N1[1];
                P.p[2] = __builtin_amdgcn_cvt_pkrtz(M1[0]*N1[0], g5);
                P.p[3] = __builtin_amdgcn_cvt_pkrtz(M1[2]*N1[2], M1[3]*N1[3]);
            }

            // stage2: D[o][e] (Wlin frag sigma-packed, bias at kc=25)
            floatx4 H0 = __builtin_amdgcn_mfma_f32_16x16x32_f16(fp[(fb+4)*64], P.v, z, 0,0,0);
            floatx4 H1 = __builtin_amdgcn_mfma_f32_16x16x32_f16(fp[(fb+5)*64], P.v, z, 0,0,0);

            // softsign -> packed B operand for stage3; bias column = 1.0
            auto ss = [](float v_) {
                return v_ * __builtin_amdgcn_rcpf(1.0f + __builtin_fabsf(v_));
            };
            H8u Hh;
            Hh.p[0] = __builtin_amdgcn_cvt_pkrtz(ss(H0[0]), ss(H0[1]));
            Hh.p[1] = __builtin_amdgcn_cvt_pkrtz(ss(H0[2]), ss(H0[3]));
            float h5 = (q == 2) ? 1.f : ss(H1[1]);
            Hh.p[2] = __builtin_amdgcn_cvt_pkrtz(ss(H1[0]), h5);
            Hh.p[3] = __builtin_amdgcn_cvt_pkrtz(ss(H1[2]), ss(H1[3]));

            // stage3: D[ch][e]; lane (e,q) reg r holds ch = 4q+r (gate ch9 @ q=2,r=1)
            oacc[a] = __builtin_amdgcn_mfma_f32_16x16x32_f16(fp[(fb+6)*64], Hh.v, z, 0,0,0);
        }

        // ---- epilogue: softmax over actors of ch9, weighted sum of ch0..8
        const int src9 = 32 + e;   // lane (e, q=2); its reg1 = ch9
        float g0 = __shfl(oacc[0][1], src9, 64);
        float g1 = __shfl(oacc[1][1], src9, 64);
        float g2 = __shfl(oacc[2][1], src9, 64);
        float mx = fmaxf(g0, fmaxf(g1, g2));
        float e0 = __expf(g0 - mx);
        float e1 = __expf(g1 - mx);
        float e2 = __expf(g2 - mx);
        float inv = __builtin_amdgcn_rcpf(e0 + e1 + e2);
        e0 *= inv; e1 *= inv; e2 *= inv;

        float res[4];
        #pragma unroll
        for (int r = 0; r < 4; ++r)
            res[r] = oacc[0][r] * e0 + oacc[1][r] * e1 + oacc[2][r] * e2;

        // ---- compact to this wave's scratch, coalesced float4 store
        if (q < 2) {
            #pragma unroll
            for (int r = 0; r < 4; ++r) ldso[e * 9 + 4 * q + r] = res[r];
        } else if (q == 2) {
            ldso[e * 9 + 8] = res[0];
        }
        // same-wave DS ordering: writes retire before the reads below issue
        if (lane < 36) {
            float4 v = *(const float4*)(ldso + lane * 4);
            *(float4*)(out + (b0 + (size_t)tt * (16 * NWAVES) + w * 16) * 9 + lane * 4) = v;
        }
    };

    // ---- software-pipelined tile loop: prefetch 1 tile ahead, ping-pong regs
    float sA[8], sB[8];
    loadT(sA, 0);
    for (int tt = 0; tt < TPB; tt += 2) {
        loadT(sB, tt + 1);
        tileCompute(sA, tt);
        if (tt + 2 < TPB) loadT(sA, tt + 2);
        tileCompute(sB, tt + 1);
    }
}

extern "C" void kernel_launch(void* const* d_in, const int* in_sizes, int n_in,
                              void* d_out, int out_size, void* d_ws, size_t ws_size,
                              hipStream_t stream) {
    const float* spatial = (const float*)d_in[0];
    // d_in[1] = car_stats: unused by the model, never read.
    const float* Wmx  = (const float*)d_in[2];
    const float* bmx  = (const float*)d_in[3];
    const float* Wnx  = (const float*)d_in[4];
    const float* bnx  = (const float*)d_in[5];
    const float* Wmy  = (const float*)d_in[6];
    const float* bmy  = (const float*)d_in[7];
    const float* Wny  = (const float*)d_in[8];
    const float* bny  = (const float*)d_in[9];
    const float* Wmz  = (const float*)d_in[10];
    const float* bmz  = (const float*)d_in[11];
    const float* Wnz  = (const float*)d_in[12];
    const float* bnz  = (const float*)d_in[13];
    const float* Wlin = (const float*)d_in[14];
    const float* blin = (const float*)d_in[15];
    const float* Wout = (const float*)d_in[16];
    const float* bout = (const float*)d_in[17];
    float* out = (float*)d_out;

    _Float16* frag = (_Float16*)d_ws;   // 21504 B

    prep_frags<<<dim3(42), dim3(256), 0, stream>>>(
        Wmx, bmx, Wnx, bnx, Wmy, bmy, Wny, bny, Wmz, bmz, Wnz, bnz,
        Wlin, blin, Wout, bout, frag);

    const int nb = in_sizes[0] / 27;           // 1048576, multiple of 16*NWAVES*TPB
    dim3 grid(nb / (16 * NWAVES * TPB));       // 1024 blocks, 8 waves each
    actor_mfma<<<grid, dim3(64 * NWAVES), 0, stream>>>(spatial, frag, out);
}

// Round 12
// 225.263 us; speedup vs baseline: 1.0263x; 1.0092x over previous
//
#include <hip/hip_runtime.h>

// CombinedActorModel R16: R12b + coalesced spatial loads via per-wave LDS slab.
// R13 (ILP) null, R14 (hoist) -7us, R15 (residency) -4us: scheduling levers
// exhausted; only instruction/resource cuts pay. Hidden binder hypothesis: the
// per-lane 108B-stride spatial scatter generates ~9x redundant L1 line-touches
// (~240 line-requests/wave-tile vs 27 compulsory) serialized on the per-CU TA.
// Fix: each wave's 16 elements are CONTIGUOUS (432 floats) -> load coalesced
// (2 masked float4/lane), stage into a PRIVATE per-wave LDS slab (no barriers:
// same-wave DS ordering), lanes read S[e][8q..] back as 8x ds_read_b32.
// Ping-pong register prefetch of the next tile's slab kept. Everything else
// (cvt_pkrtz packs, bias folded into spare K-slots, LDS frag image +
// pinned-index ds_read_b128, 512-thread blocks, TPB=4, LDS-compacted stores)
// byte-identical to R12b.

typedef _Float16 half8   __attribute__((ext_vector_type(8)));
typedef __fp16   fp16x2  __attribute__((ext_vector_type(2)));
typedef float    floatx4 __attribute__((ext_vector_type(4)));

#define NFRAG 21                    // 3 actors * (4 stage1 + 2 stage2 + 1 stage3)
#define FRAG_HALFS (NFRAG * 512)    // 10752 halfs = 21504 B
#define TPB 4                       // tiles per block (tile = 128 elements)
#define NWAVES 8                    // 512-thread blocks

__global__ __launch_bounds__(256) void prep_frags(
    const float* __restrict__ Wmx, const float* __restrict__ bmx,
    const float* __restrict__ Wnx, const float* __restrict__ bnx,
    const float* __restrict__ Wmy, const float* __restrict__ bmy,
    const float* __restrict__ Wny, const float* __restrict__ bny,
    const float* __restrict__ Wmz, const float* __restrict__ bmz,
    const float* __restrict__ Wnz, const float* __restrict__ bnz,
    const float* __restrict__ Wlin, const float* __restrict__ blin,
    const float* __restrict__ Wout, const float* __restrict__ bout,
    _Float16* __restrict__ frag)
{
    int i = threadIdx.x + blockIdx.x * blockDim.x;
    if (i >= FRAG_HALFS) return;
    int f = i >> 9, rem = i & 511;
    int lane = rem >> 3, j = rem & 7;
    int q = lane >> 4, m = lane & 15;
    int a = f / 7, idx = f % 7;
    float v = 0.f;
    if (idx < 4) {
        int c = m + ((idx & 1) ? 16 : 0);
        int k = 8 * q + j;
        bool npart = (idx >= 2);
        if (c < 10) {
            if (!npart) { if (k < 6)             v = Wmx[(a*10 + c)*6 + k];
                          else if (k == 27)      v = bmx[a*10 + c]; }
            else        { if (k >= 6 && k < 9)   v = Wnx[(a*10 + c)*3 + (k-6)];
                          else if (k == 27)      v = bnx[a*10 + c]; }
        } else if (c < 20) {
            if (!npart) { if (k >= 9 && k < 15)  v = Wmy[(a*10 + c-10)*6 + (k-9)];
                          else if (k == 27)      v = bmy[a*10 + c-10]; }
            else        { if (k >= 15 && k < 18) v = Wny[(a*10 + c-10)*3 + (k-15)];
                          else if (k == 27)      v = bny[a*10 + c-10]; }
        } else if (c < 25) {
            if (!npart) { if (k >= 18 && k < 24) v = Wmz[(a*5 + c-20)*6 + (k-18)];
                          else if (k == 27)      v = bmz[a*5 + c-20]; }
            else        { if (k >= 24 && k < 27) v = Wnz[(a*5 + c-20)*3 + (k-24)];
                          else if (k == 27)      v = bnz[a*5 + c-20]; }
        }
    } else if (idx < 6) {
        int o  = m + ((idx == 5) ? 16 : 0);
        int kc = 16 * (j >> 2) + 4 * q + (j & 3);   // sigma(q,j)
        if (o < 25) {
            if (kc < 25)       v = Wlin[(a*25 + o)*25 + kc];
            else if (kc == 25) v = blin[a*25 + o];
        }
    } else {
        int ko = 16 * (j >> 2) + 4 * q + (j & 3);
        if (m < 10) {
            if (ko < 25)       v = Wout[(a*15 + m)*25 + ko];
            else if (ko == 25) v = bout[a*15 + m];
        }
    }
    frag[(size_t)f * 512 + lane * 8 + j] = (_Float16)v;
}

__global__ __launch_bounds__(512) void actor_mfma(
    const float* __restrict__ spatial,
    const _Float16* __restrict__ frag,
    float* __restrict__ out)
{
    __shared__ _Float16 lds_f[FRAG_HALFS];       // 21504 B, block-shared constants
    __shared__ float    lds_sp[NWAVES*432 + 16]; // per-wave spatial slabs (+OOB pad)
    __shared__ float    lds_o[NWAVES * 144];     // per-wave output compaction

    const int t = threadIdx.x;
    const int lane = t & 63, w = t >> 6;
    const int q = lane >> 4, e = lane & 15;
    const size_t b0 = (size_t)blockIdx.x * (16 * NWAVES * TPB);

    // ---- cooperative frag staging: 1344 float4, once per block
    {
        const float4* gf = (const float4*)frag;
        float4* df = (float4*)lds_f;
        #pragma unroll
        for (int k = 0; k < 3; ++k) {
            int idx = t + k * 512;
            if (idx < 1344) df[idx] = gf[idx];
        }
    }

    // ---- per-lane constants (invariant across tiles)
    const float* gslab = spatial + (b0 + (size_t)w * 16) * 27;  // wave slab base
    float* const wsp   = lds_sp + w * 432;                      // LDS slab
    const float* rbase = wsp + 27 * e + 8 * q;                  // this lane's row slice
    float vbase[8];
    #pragma unroll
    for (int j = 0; j < 8; ++j) vbase[j] = ((8 * q + j) == 27) ? 1.f : 0.f;

    float* const ldso = lds_o + w * 144;
    const floatx4 z = {0.f, 0.f, 0.f, 0.f};

    __syncthreads();

    // 32-bit LDS half8-index; opaquely re-pinned per actor so the 21
    // loop-invariant ds_reads can't be hoisted into (and spill) registers.
    int fo = lane;

    // coalesced slab load: 432 contiguous floats per wave -> 2 masked float4
    auto loadG = [&](float4& r0, float4& r1, int tt) {
        const float* s_ = gslab + (size_t)tt * (16 * NWAVES * 27);
        r0 = *(const float4*)(s_ + 4 * lane);
        if (lane < 44) r1 = *(const float4*)(s_ + 256 + 4 * lane);
    };
    // same-wave LDS staging (no barrier needed: same-wave DS ordering)
    auto stage = [&](const float4& r0, const float4& r1) {
        *(float4*)(wsp + 4 * lane) = r0;
        if (lane < 44) *(float4*)(wsp + 256 + 4 * lane) = r1;
    };

    auto tileCompute = [&](int tt) {
        union H8u { half8 v; fp16x2 p[4]; };

        // lane's 8 features from the LDS slab (b32 reads, garbage past 27 masked)
        float tmp[8];
        #pragma unroll
        for (int j = 0; j < 8; ++j) {
            int k = 8 * q + j;
            float v = rbase[j];
            tmp[j] = (k < 27) ? v : vbase[j];
        }

        H8u Bs;
        #pragma unroll
        for (int p_ = 0; p_ < 4; ++p_)
            Bs.p[p_] = __builtin_amdgcn_cvt_pkrtz(tmp[2*p_], tmp[2*p_+1]);

        floatx4 oacc[3];
        #pragma unroll
        for (int a = 0; a < 3; ++a) {
            asm volatile("" : "+v"(fo));   // opaque: blocks LICM/clustering
            const half8* fp = (const half8*)lds_f + fo;
            const int fb = a * 7;
            // stage1: D[c][e]; ds_read_b128 at literal offsets feeds MFMA
            H8u P;
            {
                floatx4 M0 = __builtin_amdgcn_mfma_f32_16x16x32_f16(fp[(fb+0)*64], Bs.v, z, 0,0,0);
                floatx4 N0 = __builtin_amdgcn_mfma_f32_16x16x32_f16(fp[(fb+2)*64], Bs.v, z, 0,0,0);
                P.p[0] = __builtin_amdgcn_cvt_pkrtz(M0[0]*N0[0], M0[1]*N0[1]);
                P.p[1] = __builtin_amdgcn_cvt_pkrtz(M0[2]*N0[2], M0[3]*N0[3]);
            }
            {
                floatx4 M1 = __builtin_amdgcn_mfma_f32_16x16x32_f16(fp[(fb+1)*64], Bs.v, z, 0,0,0);
                floatx4 N1 = __builtin_amdgcn_mfma_f32_16x16x32_f16(fp[(fb+3)*64], Bs.v, z, 0,0,0);
                // sigma-packed slot kc=25 (q=2, elem 5) carries the stage2 bias
                float g5 = (q == 2) ? 1.f : M1[1]*N1[1];
                P.p[2] = __builtin_amdgcn_cvt_pkrtz(M1[0]*N1[0], g5);
                P.p[3] = __builtin_amdgcn_cvt_pkrtz(M1[2]*N1[2], M1[3]*N1[3]);
            }

            // stage2: D[o][e] (Wlin frag sigma-packed, bias at kc=25)
            floatx4 H0 = __builtin_amdgcn_mfma_f32_16x16x32_f16(fp[(fb+4)*64], P.v, z, 0,0,0);
            floatx4 H1 = __builtin_amdgcn_mfma_f32_16x16x32_f16(fp[(fb+5)*64], P.v, z, 0,0,0);

            // softsign -> packed B operand for stage3; bias column = 1.0
            auto ss = [](float v_) {
                return v_ * __builtin_amdgcn_rcpf(1.0f + __builtin_fabsf(v_));
            };
            H8u Hh;
            Hh.p[0] = __builtin_amdgcn_cvt_pkrtz(ss(H0[0]), ss(H0[1]));
            Hh.p[1] = __builtin_amdgcn_cvt_pkrtz(ss(H0[2]), ss(H0[3]));
            float h5 = (q == 2) ? 1.f : ss(H1[1]);
            Hh.p[2] = __builtin_amdgcn_cvt_pkrtz(ss(H1[0]), h5);
            Hh.p[3] = __builtin_amdgcn_cvt_pkrtz(ss(H1[2]), ss(H1[3]));

            // stage3: D[ch][e]; lane (e,q) reg r holds ch = 4q+r (gate ch9 @ q=2,r=1)
            oacc[a] = __builtin_amdgcn_mfma_f32_16x16x32_f16(fp[(fb+6)*64], Hh.v, z, 0,0,0);
        }

        // ---- epilogue: softmax over actors of ch9, weighted sum of ch0..8
        const int src9 = 32 + e;   // lane (e, q=2); its reg1 = ch9
        float g0 = __shfl(oacc[0][1], src9, 64);
        float g1 = __shfl(oacc[1][1], src9, 64);
        float g2 = __shfl(oacc[2][1], src9, 64);
        float mx = fmaxf(g0, fmaxf(g1, g2));
        float e0 = __expf(g0 - mx);
        float e1 = __expf(g1 - mx);
        float e2 = __expf(g2 - mx);
        float inv = __builtin_amdgcn_rcpf(e0 + e1 + e2);
        e0 *= inv; e1 *= inv; e2 *= inv;

        float res[4];
        #pragma unroll
        for (int r = 0; r < 4; ++r)
            res[r] = oacc[0][r] * e0 + oacc[1][r] * e1 + oacc[2][r] * e2;

        // ---- compact to this wave's scratch, coalesced float4 store
        if (q < 2) {
            #pragma unroll
            for (int r = 0; r < 4; ++r) ldso[e * 9 + 4 * q + r] = res[r];
        } else if (q == 2) {
            ldso[e * 9 + 8] = res[0];
        }
        // same-wave DS ordering: writes retire before the reads below issue
        if (lane < 36) {
            float4 v = *(const float4*)(ldso + lane * 4);
            *(float4*)(out + (b0 + (size_t)tt * (16 * NWAVES) + w * 16) * 9 + lane * 4) = v;
        }
    };

    // ---- tile loop: ping-pong register prefetch of the next slab; the LDS
    // slab itself is single-buffered (same-wave DS ordering makes it safe).
    float4 a0, a1, c0, c1;
    loadG(a0, a1, 0);
    for (int tt = 0; tt < TPB; tt += 2) {
        stage(a0, a1);                       // waits vmcnt on a-loads (prefetched)
        loadG(c0, c1, tt + 1);               // issue next slab early
        tileCompute(tt);                     // ds_reads ordered after stage writes
        stage(c0, c1);
        if (tt + 2 < TPB) loadG(a0, a1, tt + 2);
        tileCompute(tt + 1);
    }
}

extern "C" void kernel_launch(void* const* d_in, const int* in_sizes, int n_in,
                              void* d_out, int out_size, void* d_ws, size_t ws_size,
                              hipStream_t stream) {
    const float* spatial = (const float*)d_in[0];
    // d_in[1] = car_stats: unused by the model, never read.
    const float* Wmx  = (const float*)d_in[2];
    const float* bmx  = (const float*)d_in[3];
    const float* Wnx  = (const float*)d_in[4];
    const float* bnx  = (const float*)d_in[5];
    const float* Wmy  = (const float*)d_in[6];
    const float* bmy  = (const float*)d_in[7];
    const float* Wny  = (const float*)d_in[8];
    const float* bny  = (const float*)d_in[9];
    const float* Wmz  = (const float*)d_in[10];
    const float* bmz  = (const float*)d_in[11];
    const float* Wnz  = (const float*)d_in[12];
    const float* bnz  = (const float*)d_in[13];
    const float* Wlin = (const float*)d_in[14];
    const float* blin = (const float*)d_in[15];
    const float* Wout = (const float*)d_in[16];
    const float* bout = (const float*)d_in[17];
    float* out = (float*)d_out;

    _Float16* frag = (_Float16*)d_ws;   // 21504 B

    prep_frags<<<dim3(42), dim3(256), 0, stream>>>(
        Wmx, bmx, Wnx, bnx, Wmy, bmy, Wny, bny, Wmz, bmz, Wnz, bnz,
        Wlin, blin, Wout, bout, frag);

    const int nb = in_sizes[0] / 27;           // 1048576, multiple of 16*NWAVES*TPB
    dim3 grid(nb / (16 * NWAVES * TPB));       // 2048 blocks, 8 waves each
    actor_mfma<<<grid, dim3(64 * NWAVES), 0, stream>>>(spatial, frag, out);
}